// Round 9
// baseline (284.891 us; speedup 1.0000x reference)
//
#include <hip/hip_runtime.h>
#include <cstddef>

#define BATCH 4
#define SEQ   4096
#define DIM   2048
#define EPSF  1e-5f
#define TCHUNK 16
#define NROWS (TCHUNK + 3)           // 19 rows incl. 3-row warm-up history
#define CPB   (SEQ / TCHUNK)         // 256 mask chunks per batch
#define NBLK  (BATCH * CPB)          // 1024 mask blocks
#define SROWS 8                      // rows per scatter block
#define NSCAT (BATCH * (SEQ / SROWS))// 2048 scatter blocks

typedef float f4 __attribute__((ext_vector_type(4)));

__device__ __forceinline__ float wave_sum(float v) {
#pragma unroll
    for (int off = 32; off > 0; off >>= 1)
        v += __shfl_down(v, off, 64);
    return v;
}
__device__ __forceinline__ int wave_sum_i(int v) {
#pragma unroll
    for (int off = 32; off > 0; off >>= 1)
        v += __shfl_down(v, off, 64);
    return v;
}

// Phase 1: fused rmsnorm -> causal dwconv(W=4) -> silu -> (p1-p0) dot -> sign.
// TWO-PASS restructure (r8 lesson: mask is latency/barrier-bound, not BW-bound
// -- cutting 25MB of fetch changed nothing, so attack the 6-barrier serial
// structure instead):
//   pass 1: stream 19 rows, per-lane square-sum accumulators (loads fully
//           independent -> deep pipelining), 19 wave-reduces, ONE barrier.
//   pass 2: re-stream rows (block set = 152KB; L2/L3-absorbed re-read, x fits
//           in 256MB L3), rstd from LDS, conv+silu+dot in the SAME per-lane
//           summation order as the proven kernel (bit-identical signs),
//           inline per-token wave-reduce, ONE final barrier, pack.
// launch_bounds(256,3): r6 showed (256,4) clamps VGPR to 64 -> 21MB spill.
// Output: cnt[chunk] = count | (mask_bits16 << 16).
__global__ __launch_bounds__(256, 3) void mask_kernel(
    const float* __restrict__ x, const float* __restrict__ nw,
    const float* __restrict__ cw, const float* __restrict__ pw,
    unsigned int* __restrict__ cnt)
{
    __shared__ float lds_ss[NROWS][4];   // per-row, per-wave ss partials
    __shared__ float lds_acc[TCHUNK][4]; // per-token, per-wave dot partials

    const int t = threadIdx.x, lane = t & 63, wid = t >> 6;
    // XCD swizzle: seq-adjacent chunks -> same XCD (L2 reuse of shared rows)
    const int G = gridDim.x;
    const int chunk = (blockIdx.x & 7) * (G >> 3) + (blockIdx.x >> 3);
    const int b  = chunk / CPB;
    const int s0 = (chunk % CPB) * TCHUNK;
    const int d0 = 4 * t, d1 = d0 + 1024;

    // conv*norm folded (cwn), projection diff (pd)
    float cwn[8][4], pd[8];
    {
        float4 n0 = *(const float4*)(nw + d0);
        float4 n1 = *(const float4*)(nw + d1);
        float nv[8] = {n0.x, n0.y, n0.z, n0.w, n1.x, n1.y, n1.z, n1.w};
#pragma unroll
        for (int i = 0; i < 8; ++i) {
            const int d = (i < 4) ? (d0 + i) : (d1 + i - 4);
            float4 c4 = *(const float4*)(cw + 4 * d);
            cwn[i][0] = c4.x * nv[i]; cwn[i][1] = c4.y * nv[i];
            cwn[i][2] = c4.z * nv[i]; cwn[i][3] = c4.w * nv[i];
        }
        float4 a0 = *(const float4*)(pw + d0);
        float4 a1 = *(const float4*)(pw + d1);
        float4 b0 = *(const float4*)(pw + DIM + d0);
        float4 b1 = *(const float4*)(pw + DIM + d1);
        pd[0] = b0.x - a0.x; pd[1] = b0.y - a0.y; pd[2] = b0.z - a0.z; pd[3] = b0.w - a0.w;
        pd[4] = b1.x - a1.x; pd[5] = b1.y - a1.y; pd[6] = b1.z - a1.z; pd[7] = b1.w - a1.w;
    }

    const float* xb = x + (size_t)b * SEQ * DIM;

    // ---- pass 1: per-lane square-sums for all 19 rows (no barriers) ----
    float ssp[NROWS];
#pragma unroll
    for (int r = 0; r < NROWS; ++r) {
        const int s = s0 - 3 + r;
        float ss = 0.f;
        if (s >= 0) {                      // uniform (false only in chunk 0)
            const float4 a = *(const float4*)(xb + (size_t)s * DIM + d0);
            const float4 c = *(const float4*)(xb + (size_t)s * DIM + d1);
            ss += a.x * a.x; ss += a.y * a.y; ss += a.z * a.z; ss += a.w * a.w;
            ss += c.x * c.x; ss += c.y * c.y; ss += c.z * c.z; ss += c.w * c.w;
        }
        ssp[r] = ss;
    }
#pragma unroll
    for (int r = 0; r < NROWS; ++r) {
        const float ss = wave_sum(ssp[r]);
        if (lane == 0) lds_ss[r][wid] = ss;
    }
    __syncthreads();                       // barrier 1 of 2

    // ---- pass 2: re-stream rows, conv+silu+dot (no barriers in loop) ----
    float h1[8], h2[8], h3[8];
#pragma unroll
    for (int i = 0; i < 8; ++i) { h1[i] = 0.f; h2[i] = 0.f; h3[i] = 0.f; }

#pragma unroll
    for (int r = 0; r < NROWS; ++r) {
        const int s = s0 - 3 + r;
        float v[8];
        if (s >= 0) {                      // L2/L3-hot re-read
            const float4 a = *(const float4*)(xb + (size_t)s * DIM + d0);
            const float4 c = *(const float4*)(xb + (size_t)s * DIM + d1);
            v[0]=a.x; v[1]=a.y; v[2]=a.z; v[3]=a.w;
            v[4]=c.x; v[5]=c.y; v[6]=c.z; v[7]=c.w;
        } else {
#pragma unroll
            for (int i = 0; i < 8; ++i) v[i] = 0.f;
        }
        const float sum4 = lds_ss[r][0] + lds_ss[r][1]
                         + lds_ss[r][2] + lds_ss[r][3];
        const float rstd = 1.0f / sqrtf(sum4 * (1.0f / DIM) + EPSF);
        float hc[8];
#pragma unroll
        for (int i = 0; i < 8; ++i) hc[i] = v[i] * rstd;

        if (r >= 3) {                      // emit token j = r-3
            float acc = 0.f;
#pragma unroll
            for (int i = 0; i < 8; ++i) {
                const float y = cwn[i][0] * h3[i] + cwn[i][1] * h2[i]
                              + cwn[i][2] * h1[i] + cwn[i][3] * hc[i];
                const float sig = 1.0f / (1.0f + __expf(-y));
                acc += (y * sig) * pd[i];
            }
            acc = wave_sum(acc);
            if (lane == 0) lds_acc[r - 3][wid] = acc;
        }
#pragma unroll
        for (int i = 0; i < 8; ++i) { h3[i] = h2[i]; h2[i] = h1[i]; h1[i] = hc[i]; }
    }
    __syncthreads();                       // barrier 2 of 2

    // ---- pack 16 signs + count into one u32 (wave 0 only) ----
    if (wid == 0) {
        int sel = 0;
        if (lane < TCHUNK) {
            const float a = lds_acc[lane][0] + lds_acc[lane][1]
                          + lds_acc[lane][2] + lds_acc[lane][3];
            sel = (a > 0.f) ? 1 : 0;       // lane = token offset in chunk
        }
        const unsigned long long bal = __ballot(sel);
        if (lane == 0)
            cnt[chunk] = (unsigned)__popcll(bal)
                       | ((unsigned)(bal & 0xFFFFull) << 16);
    }
}

// Phase 2 (scan+scatter fused): one block per 8-row half-chunk. Each block
// rebuilds its exclusive prefix + batch total from the 256 per-batch chunk
// counts (1 KB, L2-hot; one count per thread, packed reduce gives prefix AND
// nsel at once). x loads for selected rows are issued BEFORE the reduce,
// hiding L3/HBM latency under the reduction. out is write-once -> nontemporal
// stores. NO min-waves bound: ra/rc alone is 64 VGPRs; a (256,4) bound would
// clamp to 64 VGPR and spill (round-6 lesson).
// Bijection onto [0,S): selected -> p-1, unselected -> nsel + s - p.
__global__ __launch_bounds__(256) void scatter_kernel(
    const float* __restrict__ x, const unsigned int* __restrict__ cnt,
    float* __restrict__ out)
{
    __shared__ unsigned int lds_r[4];
    const int blk  = blockIdx.x;
    const int b    = blk >> 9;            // 512 scatter blocks per batch
    const int c8   = blk & 511;
    const int mc   = c8 >> 1;             // owning mask chunk (0..255)
    const int hf   = c8 & 1;              // which 8-token half
    const int t = threadIdx.x, lane = t & 63, wid = t >> 6;

    const unsigned int* cb = cnt + b * CPB;
    const unsigned vown   = cb[mc];                 // uniform -> scalar load
    const unsigned bits16 = vown >> 16;
    const unsigned bits   = (bits16 >> (8 * hf)) & 0xFFu;

    // issue the count load for the reduce (one per thread, covers all 256) ...
    const unsigned u = cb[t];

    // ... and the selected x rows, before the reduce completes
    const int s0 = c8 * SROWS;
    const float* xb = x + (size_t)b * SEQ * DIM;
    const int d0 = 4 * t, d1 = d0 + 1024;
    const float4 z = make_float4(0.f, 0.f, 0.f, 0.f);
    float4 ra[SROWS], rc[SROWS];
#pragma unroll
    for (int j = 0; j < SROWS; ++j) {
        if ((bits >> j) & 1) {                 // uniform branch
            const float* src = xb + (size_t)(s0 + j) * DIM;
            ra[j] = *(const float4*)(src + d0);
            rc[j] = *(const float4*)(src + d1);
        } else { ra[j] = z; rc[j] = z; }
    }

    // packed reduce: low16 = exclusive-prefix contribution, high16 = total
    const int c = (int)(u & 0xFFFFu);
    int pack = ((t < mc) ? c : 0) + (c << 16);
    pack = wave_sum_i(pack);
    if (lane == 0) lds_r[wid] = (unsigned)pack;
    __syncthreads();
    const unsigned tot = lds_r[0] + lds_r[1] + lds_r[2] + lds_r[3];
    const int pre  = (int)(tot & 0xFFFFu)
                   + (hf ? __popc(bits16 & 0xFFu) : 0);
    const int nsel = (int)(tot >> 16);

    float* ob = out + (size_t)b * SEQ * DIM;
#pragma unroll
    for (int j = 0; j < SROWS; ++j) {
        const int incl = __popc(bits & ((2u << j) - 1u));   // inclusive in 8
        const int p    = pre + incl;
        const int sel  = (bits >> j) & 1;
        const int dest = sel ? (p - 1) : (nsel + s0 + j - p);
        float* o = ob + (size_t)dest * DIM;
        __builtin_nontemporal_store(*(const f4*)&ra[j], (f4*)(o + d0));
        __builtin_nontemporal_store(*(const f4*)&rc[j], (f4*)(o + d1));
    }
}

extern "C" void kernel_launch(void* const* d_in, const int* in_sizes, int n_in,
                              void* d_out, int out_size, void* d_ws, size_t ws_size,
                              hipStream_t stream) {
    const float* x  = (const float*)d_in[0];   // [B,S,D]
    const float* nw = (const float*)d_in[1];   // [D]
    const float* cw = (const float*)d_in[2];   // [D,4]
    const float* pw = (const float*)d_in[3];   // [2,D]
    float* out = (float*)d_out;                // [B,S,D]

    unsigned int* cnt = (unsigned int*)d_ws;   // NBLK u32 = 4 KB; every entry
                                               // written by mask before scatter
                                               // reads -> no memset needed
    mask_kernel<<<NBLK, 256, 0, stream>>>(x, nw, cw, pw, cnt);
    scatter_kernel<<<NSCAT, 256, 0, stream>>>(x, cnt, out);
}

// Round 11
// 276.442 us; speedup vs baseline: 1.0306x; 1.0306x over previous
//
#include <hip/hip_runtime.h>
#include <cstddef>

#define BATCH 4
#define SEQ   4096
#define DIM   2048
#define EPSF  1e-5f
#define TCHUNK 16
#define CPB   (SEQ / TCHUNK)         // 256 mask chunks per batch
#define NBLK  (BATCH * CPB)          // 1024 mask blocks
#define SROWS 8                      // rows per scatter block
#define NSCAT (BATCH * (SEQ / SROWS))// 2048 scatter blocks

typedef float f4 __attribute__((ext_vector_type(4)));

__device__ __forceinline__ float wave_sum(float v) {
#pragma unroll
    for (int off = 32; off > 0; off >>= 1)
        v += __shfl_down(v, off, 64);
    return v;
}
__device__ __forceinline__ int wave_sum_i(int v) {
#pragma unroll
    for (int off = 32; off > 0; off >>= 1)
        v += __shfl_down(v, off, 64);
    return v;
}

// Phase 1: fused rmsnorm -> causal dwconv(W=4) -> silu -> (p1-p0) dot -> sign.
// r8 group structure (proven best, 263.2us total) + ONE-GROUP REGISTER
// PREFETCH: each iteration issues group g+1's loads BEFORE group g's
// ss-reduce, so the compiler's mandatory vmcnt(0)-before-s_barrier drains
// already-overlapped loads instead of exposing fresh latency (r8 exposed it
// 5x per block). r9 lessons applied: NO two-pass re-read (L3 didn't absorb:
// +62MB HBM), NO giant flat unroll (compiler shrank to 60 VGPR and
// vmcnt-serialized). launch_bounds(256,3): r6 showed (256,4) clamps VGPR to
// 64 and spills 21MB. Ping-pong xv[2] with static indices (unrolled g).
// Output: cnt[chunk] = count | (mask_bits16 << 16).
__global__ __launch_bounds__(256, 3) void mask_kernel(
    const float* __restrict__ x, const float* __restrict__ nw,
    const float* __restrict__ cw, const float* __restrict__ pw,
    unsigned int* __restrict__ cnt)
{
    __shared__ float lds_ss[5][4][4];   // slots 0..3 = groups, 4 = warmup
    __shared__ float lds_acc[4][4][4];  // write-once slots -> no WAR hazards

    const int t = threadIdx.x, lane = t & 63, wid = t >> 6;
    // XCD swizzle: seq-adjacent chunks -> same XCD (L2 reuse of shared rows)
    const int G = gridDim.x;
    const int chunk = (blockIdx.x & 7) * (G >> 3) + (blockIdx.x >> 3);
    const int b  = chunk / CPB;
    const int s0 = (chunk % CPB) * TCHUNK;
    const int d0 = 4 * t, d1 = d0 + 1024;

    const float* xb = x + (size_t)b * SEQ * DIM;

    // ---- issue the deepest-latency loads FIRST: warmup + group 0 ----
    float wv[3][8];
#pragma unroll
    for (int w = 0; w < 3; ++w) {
        const int s = s0 - 3 + w;
        if (s >= 0) {
            const float4 a = *(const float4*)(xb + (size_t)s * DIM + d0);
            const float4 c = *(const float4*)(xb + (size_t)s * DIM + d1);
            wv[w][0]=a.x; wv[w][1]=a.y; wv[w][2]=a.z; wv[w][3]=a.w;
            wv[w][4]=c.x; wv[w][5]=c.y; wv[w][6]=c.z; wv[w][7]=c.w;
        } else {
#pragma unroll
            for (int i = 0; i < 8; ++i) wv[w][i] = 0.f;
        }
    }
    float xv[2][4][8];
#pragma unroll
    for (int j = 0; j < 4; ++j) {
        const int s = s0 + j;
        const float4 a = *(const float4*)(xb + (size_t)s * DIM + d0);
        const float4 c = *(const float4*)(xb + (size_t)s * DIM + d1);
        xv[0][j][0]=a.x; xv[0][j][1]=a.y; xv[0][j][2]=a.z; xv[0][j][3]=a.w;
        xv[0][j][4]=c.x; xv[0][j][5]=c.y; xv[0][j][6]=c.z; xv[0][j][7]=c.w;
    }

    // weight prep (L2-hot across blocks) overlaps the x-load latency
    float cwn[8][4], pd[8];
    {
        float4 n0 = *(const float4*)(nw + d0);
        float4 n1 = *(const float4*)(nw + d1);
        float nv[8] = {n0.x, n0.y, n0.z, n0.w, n1.x, n1.y, n1.z, n1.w};
#pragma unroll
        for (int i = 0; i < 8; ++i) {
            const int d = (i < 4) ? (d0 + i) : (d1 + i - 4);
            float4 c4 = *(const float4*)(cw + 4 * d);
            cwn[i][0] = c4.x * nv[i]; cwn[i][1] = c4.y * nv[i];
            cwn[i][2] = c4.z * nv[i]; cwn[i][3] = c4.w * nv[i];
        }
        float4 a0 = *(const float4*)(pw + d0);
        float4 a1 = *(const float4*)(pw + d1);
        float4 b0 = *(const float4*)(pw + DIM + d0);
        float4 b1 = *(const float4*)(pw + DIM + d1);
        pd[0] = b0.x - a0.x; pd[1] = b0.y - a0.y; pd[2] = b0.z - a0.z; pd[3] = b0.w - a0.w;
        pd[4] = b1.x - a1.x; pd[5] = b1.y - a1.y; pd[6] = b1.z - a1.z; pd[7] = b1.w - a1.w;
    }

    // ---- warm-up ss (wv in regs by first use) ----
#pragma unroll
    for (int w = 0; w < 3; ++w) {
        float ss = 0.f;
#pragma unroll
        for (int i = 0; i < 8; ++i) ss += wv[w][i] * wv[w][i];
        ss = wave_sum(ss);
        if (lane == 0) lds_ss[4][w][wid] = ss;
    }
    __syncthreads();                   // barrier A (drains warmup+g0 loads)

    float h1[8], h2[8], h3[8];
#pragma unroll
    for (int w = 0; w < 3; ++w) {
        const float sum4 = lds_ss[4][w][0] + lds_ss[4][w][1]
                         + lds_ss[4][w][2] + lds_ss[4][w][3];
        const float rstd = 1.0f / sqrtf(sum4 * (1.0f / DIM) + EPSF);
        float* h = (w == 0) ? h3 : (w == 1) ? h2 : h1;
#pragma unroll
        for (int i = 0; i < 8; ++i) h[i] = wv[w][i] * rstd;
    }

    // ---- main: 4 groups; prefetch g+1 before g's reduce+barrier ----
#pragma unroll
    for (int g = 0; g < 4; ++g) {
        if (g < 3) {                   // 1. issue next group's loads
#pragma unroll
            for (int j = 0; j < 4; ++j) {
                const int s = s0 + 4 * (g + 1) + j;
                const float4 a = *(const float4*)(xb + (size_t)s * DIM + d0);
                const float4 c = *(const float4*)(xb + (size_t)s * DIM + d1);
                xv[(g + 1) & 1][j][0]=a.x; xv[(g + 1) & 1][j][1]=a.y;
                xv[(g + 1) & 1][j][2]=a.z; xv[(g + 1) & 1][j][3]=a.w;
                xv[(g + 1) & 1][j][4]=c.x; xv[(g + 1) & 1][j][5]=c.y;
                xv[(g + 1) & 1][j][6]=c.z; xv[(g + 1) & 1][j][7]=c.w;
            }
        }
        // 2. ss for group g (xv[g&1] already resident)
#pragma unroll
        for (int j = 0; j < 4; ++j) {
            float ss = 0.f;
#pragma unroll
            for (int i = 0; i < 8; ++i) ss += xv[g & 1][j][i] * xv[g & 1][j][i];
            ss = wave_sum(ss);
            if (lane == 0) lds_ss[g][j][wid] = ss;
        }
        __syncthreads();               // 3. barrier (g+1 loads drain here)
        // 4. conv + silu + dot for group g
#pragma unroll
        for (int j = 0; j < 4; ++j) {
            const float sum4 = lds_ss[g][j][0] + lds_ss[g][j][1]
                             + lds_ss[g][j][2] + lds_ss[g][j][3];
            const float rstd = 1.0f / sqrtf(sum4 * (1.0f / DIM) + EPSF);
            float acc = 0.f;
#pragma unroll
            for (int i = 0; i < 8; ++i) {
                const float hc = xv[g & 1][j][i] * rstd;
                const float y = cwn[i][0] * h3[i] + cwn[i][1] * h2[i]
                              + cwn[i][2] * h1[i] + cwn[i][3] * hc;
                const float sig = 1.0f / (1.0f + __expf(-y));
                acc += (y * sig) * pd[i];
                h3[i] = h2[i]; h2[i] = h1[i]; h1[i] = hc;
            }
            acc = wave_sum(acc);
            if (lane == 0) lds_acc[g][j][wid] = acc;
        }
    }
    __syncthreads();                   // final: all acc slots visible

    // ---- pack 16 signs + count into one u32 (wave 0 only) ----
    if (wid == 0) {
        int sel = 0;
        if (lane < TCHUNK) {
            const int g = lane >> 2, j = lane & 3;
            const float a = lds_acc[g][j][0] + lds_acc[g][j][1]
                          + lds_acc[g][j][2] + lds_acc[g][j][3];
            sel = (a > 0.f) ? 1 : 0;   // lane = token offset in chunk
        }
        const unsigned long long bal = __ballot(sel);
        if (lane == 0)
            cnt[chunk] = (unsigned)__popcll(bal)
                       | ((unsigned)(bal & 0xFFFFull) << 16);
    }
}

// Phase 2 (scan+scatter fused): one block per 8-row half-chunk. Each block
// rebuilds its exclusive prefix + batch total from the 256 per-batch chunk
// counts (1 KB, L2-hot; one count per thread, packed reduce gives prefix AND
// nsel at once). x loads for selected rows are issued BEFORE the reduce,
// hiding L3/HBM latency under the reduction. out is write-once -> nontemporal
// stores. NO min-waves bound: ra/rc alone is 64 VGPRs; a (256,4) bound would
// clamp to 64 VGPR and spill (round-6 lesson).
// Bijection onto [0,S): selected -> p-1, unselected -> nsel + s - p.
__global__ __launch_bounds__(256) void scatter_kernel(
    const float* __restrict__ x, const unsigned int* __restrict__ cnt,
    float* __restrict__ out)
{
    __shared__ unsigned int lds_r[4];
    const int blk  = blockIdx.x;
    const int b    = blk >> 9;            // 512 scatter blocks per batch
    const int c8   = blk & 511;
    const int mc   = c8 >> 1;             // owning mask chunk (0..255)
    const int hf   = c8 & 1;              // which 8-token half
    const int t = threadIdx.x, lane = t & 63, wid = t >> 6;

    const unsigned int* cb = cnt + b * CPB;
    const unsigned vown   = cb[mc];                 // uniform -> scalar load
    const unsigned bits16 = vown >> 16;
    const unsigned bits   = (bits16 >> (8 * hf)) & 0xFFu;

    // issue the count load for the reduce (one per thread, covers all 256) ...
    const unsigned u = cb[t];

    // ... and the selected x rows, before the reduce completes
    const int s0 = c8 * SROWS;
    const float* xb = x + (size_t)b * SEQ * DIM;
    const int d0 = 4 * t, d1 = d0 + 1024;
    const float4 z = make_float4(0.f, 0.f, 0.f, 0.f);
    float4 ra[SROWS], rc[SROWS];
#pragma unroll
    for (int j = 0; j < SROWS; ++j) {
        if ((bits >> j) & 1) {                 // uniform branch
            const float* src = xb + (size_t)(s0 + j) * DIM;
            ra[j] = *(const float4*)(src + d0);
            rc[j] = *(const float4*)(src + d1);
        } else { ra[j] = z; rc[j] = z; }
    }

    // packed reduce: low16 = exclusive-prefix contribution, high16 = total
    const int c = (int)(u & 0xFFFFu);
    int pack = ((t < mc) ? c : 0) + (c << 16);
    pack = wave_sum_i(pack);
    if (lane == 0) lds_r[wid] = (unsigned)pack;
    __syncthreads();
    const unsigned tot = lds_r[0] + lds_r[1] + lds_r[2] + lds_r[3];
    const int pre  = (int)(tot & 0xFFFFu)
                   + (hf ? __popc(bits16 & 0xFFu) : 0);
    const int nsel = (int)(tot >> 16);

    float* ob = out + (size_t)b * SEQ * DIM;
#pragma unroll
    for (int j = 0; j < SROWS; ++j) {
        const int incl = __popc(bits & ((2u << j) - 1u));   // inclusive in 8
        const int p    = pre + incl;
        const int sel  = (bits >> j) & 1;
        const int dest = sel ? (p - 1) : (nsel + s0 + j - p);
        float* o = ob + (size_t)dest * DIM;
        __builtin_nontemporal_store(*(const f4*)&ra[j], (f4*)(o + d0));
        __builtin_nontemporal_store(*(const f4*)&rc[j], (f4*)(o + d1));
    }
}

extern "C" void kernel_launch(void* const* d_in, const int* in_sizes, int n_in,
                              void* d_out, int out_size, void* d_ws, size_t ws_size,
                              hipStream_t stream) {
    const float* x  = (const float*)d_in[0];   // [B,S,D]
    const float* nw = (const float*)d_in[1];   // [D]
    const float* cw = (const float*)d_in[2];   // [D,4]
    const float* pw = (const float*)d_in[3];   // [2,D]
    float* out = (float*)d_out;                // [B,S,D]

    unsigned int* cnt = (unsigned int*)d_ws;   // NBLK u32 = 4 KB; every entry
                                               // written by mask before scatter
                                               // reads -> no memset needed
    mask_kernel<<<NBLK, 256, 0, stream>>>(x, nw, cw, pw, cnt);
    scatter_kernel<<<NSCAT, 256, 0, stream>>>(x, cnt, out);
}

// Round 13
// 259.731 us; speedup vs baseline: 1.0969x; 1.0643x over previous
//
#include <hip/hip_runtime.h>
#include <cstddef>

#define BATCH 4
#define SEQ   4096
#define DIM   2048
#define EPSF  1e-5f
#define TCHUNK 16
#define CPB   (SEQ / TCHUNK)         // 256 mask chunks per batch
#define NBLK  (BATCH * CPB)          // 1024 mask blocks
#define SROWS 8                      // rows per scatter block
#define NSCAT (BATCH * (SEQ / SROWS))// 2048 scatter blocks

typedef float f4 __attribute__((ext_vector_type(4)));

__device__ __forceinline__ float wave_sum(float v) {
#pragma unroll
    for (int off = 32; off > 0; off >>= 1)
        v += __shfl_down(v, off, 64);
    return v;
}
__device__ __forceinline__ int wave_sum_i(int v) {
#pragma unroll
    for (int off = 32; off > 0; off >>= 1)
        v += __shfl_down(v, off, 64);
    return v;
}

// Phase 1: fused rmsnorm -> causal dwconv(W=4) -> silu -> (p1-p0) dot -> sign.
// r8 group structure (proven best) re-geometried to 512 THREADS x 4 CHANNELS
// per thread (was 256 x 8). Rationale (r6/r9/r11 post-mortems): the 8-ch
// working set (~130 floats) sits at the allocator's spill cliff -- every
// attempt to add ILP (prefetch r11, flat unroll r9) or cap registers (r6)
// spilled or serialized. Halving per-thread state (~75 VGPR) doubles
// occupancy (16 waves/CU vs ~10) for latency hiding WITHOUT touching the
// spill cliff. One float4 per row per thread. No prefetch, no ping-pong.
// launch_bounds(512,4): VGPR cap 128 -- big headroom over ~75 estimate.
// Output: cnt[chunk] = count | (mask_bits16 << 16).
__global__ __launch_bounds__(512, 4) void mask_kernel(
    const float* __restrict__ x, const float* __restrict__ nw,
    const float* __restrict__ cw, const float* __restrict__ pw,
    unsigned int* __restrict__ cnt)
{
    __shared__ float lds_ss[5][4][8];   // [slot][tok-in-group][wave 0..7]
    __shared__ float lds_acc[4][4][8];  // write-once slots -> no WAR hazards

    const int t = threadIdx.x, lane = t & 63, wid = t >> 6;
    // XCD swizzle: seq-adjacent chunks -> same XCD (L2 reuse of shared rows)
    const int G = gridDim.x;
    const int chunk = (blockIdx.x & 7) * (G >> 3) + (blockIdx.x >> 3);
    const int b  = chunk / CPB;
    const int s0 = (chunk % CPB) * TCHUNK;
    const int d0 = 4 * t;                  // 512 thr x 4 ch = 2048 = DIM

    // conv*norm folded (cwn), projection diff (pd) -- 4 channels per thread
    float cwn[4][4], pd[4];
    {
        const float4 nv = *(const float4*)(nw + d0);
        const float nva[4] = {nv.x, nv.y, nv.z, nv.w};
#pragma unroll
        for (int i = 0; i < 4; ++i) {
            const float4 c4 = *(const float4*)(cw + 4 * (d0 + i));
            cwn[i][0] = c4.x * nva[i]; cwn[i][1] = c4.y * nva[i];
            cwn[i][2] = c4.z * nva[i]; cwn[i][3] = c4.w * nva[i];
        }
        const float4 a0 = *(const float4*)(pw + d0);
        const float4 b0 = *(const float4*)(pw + DIM + d0);
        pd[0] = b0.x - a0.x; pd[1] = b0.y - a0.y;
        pd[2] = b0.z - a0.z; pd[3] = b0.w - a0.w;
    }

    const float* xb = x + (size_t)b * SEQ * DIM;
    float h1[4], h2[4], h3[4];   // normalized rows s-1, s-2, s-3

    // ---- warm-up: tokens s0-3..s0-1 (1 barrier) ----
    {
        float wv[3][4];
#pragma unroll
        for (int w = 0; w < 3; ++w) {
            const int s = s0 - 3 + w;
            if (s >= 0) {
                const float4 a = *(const float4*)(xb + (size_t)s * DIM + d0);
                wv[w][0]=a.x; wv[w][1]=a.y; wv[w][2]=a.z; wv[w][3]=a.w;
            } else {
#pragma unroll
                for (int i = 0; i < 4; ++i) wv[w][i] = 0.f;
            }
            float ss = 0.f;
#pragma unroll
            for (int i = 0; i < 4; ++i) ss += wv[w][i] * wv[w][i];
            ss = wave_sum(ss);
            if (lane == 0) lds_ss[4][w][wid] = ss;
        }
        __syncthreads();
#pragma unroll
        for (int w = 0; w < 3; ++w) {
            float sum8 = 0.f;
#pragma unroll
            for (int u = 0; u < 8; ++u) sum8 += lds_ss[4][w][u];
            const float rstd = 1.0f / sqrtf(sum8 * (1.0f / DIM) + EPSF);
            float* h = (w == 0) ? h3 : (w == 1) ? h2 : h1;
#pragma unroll
            for (int i = 0; i < 4; ++i) h[i] = wv[w][i] * rstd;
        }
    }

    // ---- main: 4 groups of 4 tokens, 1 barrier each + 1 final ----
#pragma unroll
    for (int g = 0; g < 4; ++g) {
        float xv[4][4];
#pragma unroll
        for (int j = 0; j < 4; ++j) {
            const int s = s0 + 4 * g + j;
            const float4 a = *(const float4*)(xb + (size_t)s * DIM + d0);
            xv[j][0]=a.x; xv[j][1]=a.y; xv[j][2]=a.z; xv[j][3]=a.w;
        }
#pragma unroll
        for (int j = 0; j < 4; ++j) {
            float ss = 0.f;
#pragma unroll
            for (int i = 0; i < 4; ++i) ss += xv[j][i] * xv[j][i];
            ss = wave_sum(ss);
            if (lane == 0) lds_ss[g][j][wid] = ss;
        }
        __syncthreads();   // orders this group's ss writes
#pragma unroll
        for (int j = 0; j < 4; ++j) {
            float sum8 = 0.f;
#pragma unroll
            for (int u = 0; u < 8; ++u) sum8 += lds_ss[g][j][u];
            const float rstd = 1.0f / sqrtf(sum8 * (1.0f / DIM) + EPSF);
            float acc = 0.f;
#pragma unroll
            for (int i = 0; i < 4; ++i) {
                const float hc = xv[j][i] * rstd;
                const float y = cwn[i][0] * h3[i] + cwn[i][1] * h2[i]
                              + cwn[i][2] * h1[i] + cwn[i][3] * hc;
                const float sig = 1.0f / (1.0f + __expf(-y));
                acc += (y * sig) * pd[i];
                h3[i] = h2[i]; h2[i] = h1[i]; h1[i] = hc;
            }
            acc = wave_sum(acc);
            if (lane == 0) lds_acc[g][j][wid] = acc;
        }
    }
    __syncthreads();   // final: all 4 groups' acc slots visible

    // ---- pack 16 signs + count into one u32 (wave 0 only) ----
    if (wid == 0) {
        int sel = 0;
        if (lane < TCHUNK) {
            const int g = lane >> 2, j = lane & 3;
            float a = 0.f;
#pragma unroll
            for (int u = 0; u < 8; ++u) a += lds_acc[g][j][u];
            sel = (a > 0.f) ? 1 : 0;   // lane = token offset in chunk
        }
        const unsigned long long bal = __ballot(sel);
        if (lane == 0)
            cnt[chunk] = (unsigned)__popcll(bal)
                       | ((unsigned)(bal & 0xFFFFull) << 16);
    }
}

// Phase 2 (scan+scatter fused): one block per 8-row half-chunk. Each block
// rebuilds its exclusive prefix + batch total from the 256 per-batch chunk
// counts (1 KB, L2-hot; one count per thread, packed reduce gives prefix AND
// nsel at once). x loads for selected rows are issued BEFORE the reduce,
// hiding L3/HBM latency under the reduction. out is write-once -> nontemporal
// stores. NO min-waves bound: ra/rc alone is 64 VGPRs; a (256,4) bound would
// clamp to 64 VGPR and spill (round-6 lesson).
// Bijection onto [0,S): selected -> p-1, unselected -> nsel + s - p.
__global__ __launch_bounds__(256) void scatter_kernel(
    const float* __restrict__ x, const unsigned int* __restrict__ cnt,
    float* __restrict__ out)
{
    __shared__ unsigned int lds_r[4];
    const int blk  = blockIdx.x;
    const int b    = blk >> 9;            // 512 scatter blocks per batch
    const int c8   = blk & 511;
    const int mc   = c8 >> 1;             // owning mask chunk (0..255)
    const int hf   = c8 & 1;              // which 8-token half
    const int t = threadIdx.x, lane = t & 63, wid = t >> 6;

    const unsigned int* cb = cnt + b * CPB;
    const unsigned vown   = cb[mc];                 // uniform -> scalar load
    const unsigned bits16 = vown >> 16;
    const unsigned bits   = (bits16 >> (8 * hf)) & 0xFFu;

    // issue the count load for the reduce (one per thread, covers all 256) ...
    const unsigned u = cb[t];

    // ... and the selected x rows, before the reduce completes
    const int s0 = c8 * SROWS;
    const float* xb = x + (size_t)b * SEQ * DIM;
    const int d0 = 4 * t, d1 = d0 + 1024;
    const float4 z = make_float4(0.f, 0.f, 0.f, 0.f);
    float4 ra[SROWS], rc[SROWS];
#pragma unroll
    for (int j = 0; j < SROWS; ++j) {
        if ((bits >> j) & 1) {                 // uniform branch
            const float* src = xb + (size_t)(s0 + j) * DIM;
            ra[j] = *(const float4*)(src + d0);
            rc[j] = *(const float4*)(src + d1);
        } else { ra[j] = z; rc[j] = z; }
    }

    // packed reduce: low16 = exclusive-prefix contribution, high16 = total
    const int c = (int)(u & 0xFFFFu);
    int pack = ((t < mc) ? c : 0) + (c << 16);
    pack = wave_sum_i(pack);
    if (lane == 0) lds_r[wid] = (unsigned)pack;
    __syncthreads();
    const unsigned tot = lds_r[0] + lds_r[1] + lds_r[2] + lds_r[3];
    const int pre  = (int)(tot & 0xFFFFu)
                   + (hf ? __popc(bits16 & 0xFFu) : 0);
    const int nsel = (int)(tot >> 16);

    float* ob = out + (size_t)b * SEQ * DIM;
#pragma unroll
    for (int j = 0; j < SROWS; ++j) {
        const int incl = __popc(bits & ((2u << j) - 1u));   // inclusive in 8
        const int p    = pre + incl;
        const int sel  = (bits >> j) & 1;
        const int dest = sel ? (p - 1) : (nsel + s0 + j - p);
        float* o = ob + (size_t)dest * DIM;
        __builtin_nontemporal_store(*(const f4*)&ra[j], (f4*)(o + d0));
        __builtin_nontemporal_store(*(const f4*)&rc[j], (f4*)(o + d1));
    }
}

extern "C" void kernel_launch(void* const* d_in, const int* in_sizes, int n_in,
                              void* d_out, int out_size, void* d_ws, size_t ws_size,
                              hipStream_t stream) {
    const float* x  = (const float*)d_in[0];   // [B,S,D]
    const float* nw = (const float*)d_in[1];   // [D]
    const float* cw = (const float*)d_in[2];   // [D,4]
    const float* pw = (const float*)d_in[3];   // [2,D]
    float* out = (float*)d_out;                // [B,S,D]

    unsigned int* cnt = (unsigned int*)d_ws;   // NBLK u32 = 4 KB; every entry
                                               // written by mask before scatter
                                               // reads -> no memset needed
    mask_kernel<<<NBLK, 512, 0, stream>>>(x, nw, cw, pw, cnt);
    scatter_kernel<<<NSCAT, 256, 0, stream>>>(x, cnt, out);
}